// Round 1
// baseline (634.013 us; speedup 1.0000x reference)
//
#include <hip/hip_runtime.h>
#include <hip/hip_fp16.h>

#define NUM_LEARNERS 50000
#define NUM_SCENES   2000
#define EMBED_DIM    128

typedef _Float16 half2v __attribute__((ext_vector_type(2)));

// Kernel 1: precompute mlp_out[j][d] = relu(j*W1+b1) @ W2 + b2, stored fp16.
// 2000*128 = 256000 elems; trivial cost.
__global__ __launch_bounds__(256) void mlp_table_kernel(
    const float* __restrict__ W1, const float* __restrict__ b1,
    const float* __restrict__ W2, const float* __restrict__ b2,
    _Float16* __restrict__ mlp)
{
    int t = blockIdx.x * 256 + threadIdx.x;
    if (t >= NUM_SCENES * EMBED_DIM) return;
    int j = t >> 7;          // scene index
    int d = t & 127;         // embed dim
    float x = (float)j;
    float acc = b2[d];
#pragma unroll
    for (int k = 0; k < 16; ++k) {
        float h = fmaf(x, W1[k], b1[k]);
        h = fmaxf(h, 0.0f);
        acc = fmaf(h, W2[k * EMBED_DIM + d], acc);
    }
    mlp[t] = (_Float16)acc;  // RTN; fp16 rel err 2^-12, no overflow risk (needs ~11 sigma)
}

// Kernel 2: one wave per learner row.
// Phase 1: float4 scan of the row, ballot-compaction of nonzero col indices
//          into per-wave LDS ushort list (no atomics; count via popcount).
// Phase 2: lane l owns dims 2l/2l+1; gather half2 per listed index,
//          fp32 accumulate, scale by 1/max(count,1), coalesced float2 store.
__global__ __launch_bounds__(256) void gather_mean_kernel(
    const float* __restrict__ M, const _Float16* __restrict__ mlp,
    float* __restrict__ out)
{
    __shared__ unsigned short idxbuf[4][NUM_SCENES];   // 16000 B -> 8 blocks/CU
    const int  wave = threadIdx.x >> 6;
    const int  lane = threadIdx.x & 63;
    const long row  = (long)blockIdx.x * 4 + wave;

    const float4* __restrict__ M4 = (const float4*)(M + row * NUM_SCENES); // 8000B rows, 16B aligned
    unsigned short* myidx = idxbuf[wave];

    int count = 0;
    const unsigned long long below = (1ull << lane) - 1ull;
#pragma unroll
    for (int it = 0; it < 8; ++it) {           // 500 float4 per row, 64 lanes
        int c4 = it * 64 + lane;
        float4 v = make_float4(0.f, 0.f, 0.f, 0.f);
        if (c4 < 500) v = M4[c4];
        float vals[4] = {v.x, v.y, v.z, v.w};
#pragma unroll
        for (int c = 0; c < 4; ++c) {
            bool nz = (vals[c] != 0.0f);
            unsigned long long m = __ballot(nz);
            if (nz) {
                int pos = count + __popcll(m & below);
                myidx[pos] = (unsigned short)(c4 * 4 + c);
            }
            count += __popcll(m);              // wave-uniform running total
        }
    }

    // Phase 2: gather-mean. Wave reads a contiguous 256B table row per index
    // (L2-resident: table is 512KB vs 4MiB per-XCD L2).
    float ax = 0.f, ay = 0.f;
    const half2v* __restrict__ mlp2 = (const half2v*)mlp;
    const int base2 = lane;                    // element offset within a table row (in half2)
#pragma unroll 4
    for (int n = 0; n < count; ++n) {
        int j = myidx[n];
        half2v p = mlp2[j * 64 + base2];
        ax += (float)p.x;
        ay += (float)p.y;
    }

    float inv = 1.0f / (float)(count > 0 ? count : 1);
    float2 r = make_float2(ax * inv, ay * inv);
    ((float2*)out)[row * 64 + lane] = r;       // coalesced 512B per wave
}

extern "C" void kernel_launch(void* const* d_in, const int* in_sizes, int n_in,
                              void* d_out, int out_size, void* d_ws, size_t ws_size,
                              hipStream_t stream) {
    const float* M  = (const float*)d_in[0];   // [50000, 2000]
    const float* W1 = (const float*)d_in[1];   // [1, 16]
    const float* b1 = (const float*)d_in[2];   // [16]
    const float* W2 = (const float*)d_in[3];   // [16, 128]
    const float* b2 = (const float*)d_in[4];   // [128]
    float* out = (float*)d_out;                // [50000, 128]

    _Float16* mlp = (_Float16*)d_ws;           // 2000*128*2 = 512 KB scratch

    mlp_table_kernel<<<(NUM_SCENES * EMBED_DIM + 255) / 256, 256, 0, stream>>>(
        W1, b1, W2, b2, mlp);
    gather_mean_kernel<<<NUM_LEARNERS / 4, 256, 0, stream>>>(M, mlp, out);
}

// Round 2
// 564.823 us; speedup vs baseline: 1.1225x; 1.1225x over previous
//
#include <hip/hip_runtime.h>

#define NUM_LEARNERS 50000
#define NUM_SCENES   2000
#define EMBED_DIM    128
#define HID          16

// Kernel 1: h_table[j][k] = relu(j*W1[k] + b1[k]), fp32, [2000][16] = 128 KB.
// Key algebra: sum_{j in nz} mlp[j] = W2^T (sum_{j in nz} h(j)) + count*b2,
// so the per-row gather only needs 16 dims, not 128 (8x traffic/VALU cut).
__global__ __launch_bounds__(256) void h_table_kernel(
    const float* __restrict__ W1, const float* __restrict__ b1,
    float* __restrict__ htab)
{
    int t = blockIdx.x * 256 + threadIdx.x;
    if (t >= NUM_SCENES * HID) return;
    int j = t >> 4;   // scene index
    int k = t & 15;   // hidden dim
    htab[t] = fmaxf(fmaf((float)j, W1[k], b1[k]), 0.0f);
}

// Kernel 2: one wave per learner row.
// Phase 1: float4 scan, ballot-compaction of nonzero col indices into LDS.
// Phase 2: 16 indices/iter (4 lanes x float4 per 64B table row), fp32 acc;
//          butterfly-reduce over index groups; 16-shfl broadcast;
//          epilogue matvec W2^T s + count*b2, scaled by 1/max(count,1).
__global__ __launch_bounds__(256) void gather_mean_kernel(
    const float* __restrict__ M, const float* __restrict__ htab,
    const float* __restrict__ W2, const float* __restrict__ b2,
    float* __restrict__ out)
{
    __shared__ unsigned short idxbuf[4][NUM_SCENES];   // 16000 B -> 8 blocks/CU
    const int  wave = threadIdx.x >> 6;
    const int  lane = threadIdx.x & 63;
    const long row  = (long)blockIdx.x * 4 + wave;

    const float4* __restrict__ M4 = (const float4*)(M + row * NUM_SCENES); // 8000B rows
    unsigned short* myidx = idxbuf[wave];

    int count = 0;
#pragma unroll
    for (int it = 0; it < 8; ++it) {             // 500 float4 per row
        int c4 = it * 64 + lane;
        float4 v = make_float4(0.f, 0.f, 0.f, 0.f);
        if (c4 < 500) v = M4[c4];
        float vals[4] = {v.x, v.y, v.z, v.w};
#pragma unroll
        for (int c = 0; c < 4; ++c) {
            bool nz = (vals[c] != 0.0f);
            unsigned long long m = __ballot(nz);
            if (nz) {
                int below = __builtin_amdgcn_mbcnt_hi(
                    (unsigned)(m >> 32),
                    __builtin_amdgcn_mbcnt_lo((unsigned)m, 0));
                myidx[count + below] = (unsigned short)(c4 * 4 + c);
            }
            count += __popcll(m);                // wave-uniform running total
        }
    }

    __syncthreads();  // drain ds_writes before dynamic-indexed reads

    // Phase 2: gather-sum of 16-dim h rows. Lane l: group g=l>>2 takes index
    // n+g, sub=l&3 covers dims 4*sub..4*sub+3 (float4 of the 64B table row).
    const int g   = lane >> 2;
    const int sub = lane & 3;
    const float4* __restrict__ T4 = (const float4*)htab;   // row j = T4[j*4+sub]

    float4 acc = make_float4(0.f, 0.f, 0.f, 0.f);
    for (int n = 0; n < count; n += 16) {
        int i = n + g;
        if (i < count) {                         // divergent only on last iter
            int j = myidx[i];
            float4 v = T4[j * 4 + sub];
            acc.x += v.x; acc.y += v.y; acc.z += v.z; acc.w += v.w;
        }
    }

    // Reduce across the 16 index-groups: butterfly over strides 4,8,16,32.
#pragma unroll
    for (int off = 4; off < 64; off <<= 1) {
        acc.x += __shfl_xor(acc.x, off);
        acc.y += __shfl_xor(acc.y, off);
        acc.z += __shfl_xor(acc.z, off);
        acc.w += __shfl_xor(acc.w, off);
    }
    // Lane l now holds s[4*(l&3)+c]; broadcast all 16 to every lane.
    float s[HID];
#pragma unroll
    for (int a = 0; a < 4; ++a) {
        s[4 * a + 0] = __shfl(acc.x, a);
        s[4 * a + 1] = __shfl(acc.y, a);
        s[4 * a + 2] = __shfl(acc.z, a);
        s[4 * a + 3] = __shfl(acc.w, a);
    }

    // Epilogue: emb[d] = (sum_k s[k]*W2[k][d] + count*b2[d]) / max(count,1).
    // Lane l owns dims 2l, 2l+1. W2/b2 are 8KB/512B -> L1-hot.
    const float cnt = (float)count;
    const float inv = 1.0f / fmaxf(cnt, 1.0f);
    const float2* __restrict__ W2v = (const float2*)W2;    // [16][64] float2
    float2 bv = ((const float2*)b2)[lane];
    float e0 = cnt * bv.x;
    float e1 = cnt * bv.y;
#pragma unroll
    for (int k = 0; k < HID; ++k) {
        float2 w = W2v[k * 64 + lane];
        e0 = fmaf(s[k], w.x, e0);
        e1 = fmaf(s[k], w.y, e1);
    }
    ((float2*)out)[row * 64 + lane] = make_float2(e0 * inv, e1 * inv);
}

extern "C" void kernel_launch(void* const* d_in, const int* in_sizes, int n_in,
                              void* d_out, int out_size, void* d_ws, size_t ws_size,
                              hipStream_t stream) {
    const float* M  = (const float*)d_in[0];   // [50000, 2000]
    const float* W1 = (const float*)d_in[1];   // [1, 16]
    const float* b1 = (const float*)d_in[2];   // [16]
    const float* W2 = (const float*)d_in[3];   // [16, 128]
    const float* b2 = (const float*)d_in[4];   // [128]
    float* out = (float*)d_out;                // [50000, 128]

    float* htab = (float*)d_ws;                // 2000*16*4 = 128 KB scratch

    h_table_kernel<<<(NUM_SCENES * HID + 255) / 256, 256, 0, stream>>>(W1, b1, htab);
    gather_mean_kernel<<<NUM_LEARNERS / 4, 256, 0, stream>>>(M, htab, W2, b2, out);
}

// Round 3
// 534.534 us; speedup vs baseline: 1.1861x; 1.0567x over previous
//
#include <hip/hip_runtime.h>

#define NUM_LEARNERS 50000
#define NUM_SCENES   2000
#define EMBED_DIM    128
#define HID          16

// Single fused kernel, one wave per learner row.
//
// Algebra: sum_{j in nz} mlp[j] = W2^T (sum_{j in nz} h(j)) + count*b2, and
// h(j)[k] = relu(j*W1[k]+b1[k]) is 3 VALU ops -- cheaper than any table
// gather. So: compact nz column indices (phase 1), accumulate the 16-dim
// h-sum in registers (phase 2), tiny matvec epilogue. No workspace, no
// second kernel, no global loads in phase 2.
__global__ __launch_bounds__(256) void fused_gather_mean_kernel(
    const float* __restrict__ M,
    const float* __restrict__ W1, const float* __restrict__ b1,
    const float* __restrict__ W2, const float* __restrict__ b2,
    float* __restrict__ out)
{
    __shared__ unsigned short idxbuf[4][NUM_SCENES];   // 16000 B -> 8 blocks/CU
    const int  wave = threadIdx.x >> 6;
    const int  lane = threadIdx.x & 63;
    const long row  = (long)blockIdx.x * 4 + wave;

    // Lane roles for phase 2: group g takes index n+g, sub covers h-dims
    // 4*sub..4*sub+3. Per-lane W1/b1 slice loaded once (L1-hot, 64/64 B).
    const int g   = lane >> 2;
    const int sub = lane & 3;
    float w1v[4], b1v[4];
#pragma unroll
    for (int c = 0; c < 4; ++c) {
        w1v[c] = W1[4 * sub + c];
        b1v[c] = b1[4 * sub + c];
    }

    const float4* __restrict__ M4 = (const float4*)(M + row * NUM_SCENES); // 8000B rows
    unsigned short* myidx = idxbuf[wave];

    // ---- Phase 1: coalesced scan + ballot-compaction (order irrelevant) ----
    int count = 0;
#pragma unroll
    for (int it = 0; it < 8; ++it) {             // 500 float4 per row
        int c4 = it * 64 + lane;
        float4 v = make_float4(0.f, 0.f, 0.f, 0.f);
        if (c4 < 500) v = M4[c4];
        float vals[4] = {v.x, v.y, v.z, v.w};
#pragma unroll
        for (int c = 0; c < 4; ++c) {
            bool nz = (vals[c] != 0.0f);
            unsigned long long m = __ballot(nz);
            if (nz) {
                int below = __builtin_amdgcn_mbcnt_hi(
                    (unsigned)(m >> 32),
                    __builtin_amdgcn_mbcnt_lo((unsigned)m, 0));
                myidx[count + below] = (unsigned short)(c4 * 4 + c);
            }
            count += __popcll(m);                // wave-uniform running total
        }
    }

    __syncthreads();  // drain ds_writes before dynamic-indexed reads

    // ---- Phase 2: in-register h-sum over compacted indices ----
    // 16 indices per step; lane computes h[4*sub+c] for index n+g inline.
    float4 acc = make_float4(0.f, 0.f, 0.f, 0.f);
#pragma unroll 2
    for (int n = 0; n < count; n += 16) {
        int   i     = n + g;
        bool  valid = (i < count);
        int   isafe = valid ? i : 0;             // count>=1 inside loop
        float x     = (float)myidx[isafe];       // broadcast ds_read_u16
        float mval  = valid ? 1.0f : 0.0f;
#pragma unroll
        for (int c = 0; c < 4; ++c) {
            float h = fmaxf(fmaf(x, w1v[c], b1v[c]), 0.0f);
            (&acc.x)[c] = fmaf(h, mval, (&acc.x)[c]);
        }
    }

    // Reduce across the 16 index-groups: butterfly over strides 4,8,16,32.
#pragma unroll
    for (int off = 4; off < 64; off <<= 1) {
        acc.x += __shfl_xor(acc.x, off);
        acc.y += __shfl_xor(acc.y, off);
        acc.z += __shfl_xor(acc.z, off);
        acc.w += __shfl_xor(acc.w, off);
    }
    // Lane l holds s[4*(l&3)+c]; broadcast all 16 to every lane.
    float s[HID];
#pragma unroll
    for (int a = 0; a < 4; ++a) {
        s[4 * a + 0] = __shfl(acc.x, a);
        s[4 * a + 1] = __shfl(acc.y, a);
        s[4 * a + 2] = __shfl(acc.z, a);
        s[4 * a + 3] = __shfl(acc.w, a);
    }

    // ---- Epilogue: emb[d] = (sum_k s[k]*W2[k][d] + count*b2[d]) / max(count,1)
    // Lane l owns dims 2l, 2l+1. W2 (8KB) / b2 (512B) are L1-hot.
    const float cnt = (float)count;
    const float inv = 1.0f / fmaxf(cnt, 1.0f);
    const float2* __restrict__ W2v = (const float2*)W2;    // [16][64] float2
    float2 bv = ((const float2*)b2)[lane];
    float e0 = cnt * bv.x;
    float e1 = cnt * bv.y;
#pragma unroll
    for (int k = 0; k < HID; ++k) {
        float2 w = W2v[k * 64 + lane];
        e0 = fmaf(s[k], w.x, e0);
        e1 = fmaf(s[k], w.y, e1);
    }
    ((float2*)out)[row * 64 + lane] = make_float2(e0 * inv, e1 * inv);
}

extern "C" void kernel_launch(void* const* d_in, const int* in_sizes, int n_in,
                              void* d_out, int out_size, void* d_ws, size_t ws_size,
                              hipStream_t stream) {
    const float* M  = (const float*)d_in[0];   // [50000, 2000]
    const float* W1 = (const float*)d_in[1];   // [1, 16]
    const float* b1 = (const float*)d_in[2];   // [16]
    const float* W2 = (const float*)d_in[3];   // [16, 128]
    const float* b2 = (const float*)d_in[4];   // [128]
    float* out = (float*)d_out;                // [50000, 128]

    fused_gather_mean_kernel<<<NUM_LEARNERS / 4, 256, 0, stream>>>(
        M, W1, b1, W2, b2, out);
}

// Round 4
// 518.882 us; speedup vs baseline: 1.2219x; 1.0302x over previous
//
#include <hip/hip_runtime.h>

#define NUM_LEARNERS 50000
#define NUM_SCENES   2000
#define EMBED_DIM    128
#define HID          16

// Single fused kernel, one wave per learner row.
//
// Algebra: sum_{j in nz} mlp[j] = W2^T (sum_{j in nz} h(j)) + count*b2, with
// h(j)[k] = relu(j*W1[k]+b1[k]) computed inline (3 VALU ops/dim).
//
// R4 changes vs R3 (theory: scan was global-load-LATENCY bound, VGPR=12
// showed the compiler serialized the row loads):
//  - Phase 0 prefetches the whole 8000B row into 8 float4 registers before
//    any compaction work -> 8 loads in flight per wave.
//  - Phase 2 reads indices as ds_read_b64 (4 ushort per 4-lane group,
//    broadcast) -> 4 LDS reads total instead of ~13 serial ds_read_u16.
__global__ __launch_bounds__(256) void fused_gather_mean_kernel(
    const float* __restrict__ M,
    const float* __restrict__ W1, const float* __restrict__ b1,
    const float* __restrict__ W2, const float* __restrict__ b2,
    float* __restrict__ out)
{
    // 2048-entry rows: phase-2 reads groups of 4 up to index 2047 -> in-bounds.
    __shared__ unsigned short idxbuf[4][2048];         // 16384 B -> 8 blocks/CU
    const int  wave = threadIdx.x >> 6;
    const int  lane = threadIdx.x & 63;
    const long row  = (long)blockIdx.x * 4 + wave;

    // Lane roles for phase 2: group g = lane>>2 consumes 4 consecutive
    // indices per iteration; sub = lane&3 covers h-dims 4*sub..4*sub+3.
    const int g   = lane >> 2;
    const int sub = lane & 3;
    float w1v[4], b1v[4];
#pragma unroll
    for (int c = 0; c < 4; ++c) {
        w1v[c] = W1[4 * sub + c];
        b1v[c] = b1[4 * sub + c];
    }

    const float4* __restrict__ M4 = (const float4*)(M + row * NUM_SCENES); // 8000B row
    unsigned short* myidx = idxbuf[wave];

    // ---- Phase 0: prefetch the full row (8 independent dwordx4 loads) ----
    float4 v[8];
#pragma unroll
    for (int it = 0; it < 8; ++it) {
        int c4 = it * 64 + lane;                 // < 448 for it<7 (no branch)
        if (c4 < 500) v[it] = M4[c4];
        else          v[it] = make_float4(0.f, 0.f, 0.f, 0.f);
    }

    // ---- Phase 1: ballot-compaction of nonzero column indices ----
    int count = 0;
#pragma unroll
    for (int it = 0; it < 8; ++it) {
        int c4 = it * 64 + lane;
        float vals[4] = {v[it].x, v[it].y, v[it].z, v[it].w};
#pragma unroll
        for (int c = 0; c < 4; ++c) {
            bool nz = (vals[c] != 0.0f);
            unsigned long long m = __ballot(nz);
            if (nz) {
                int below = __builtin_amdgcn_mbcnt_hi(
                    (unsigned)(m >> 32),
                    __builtin_amdgcn_mbcnt_lo((unsigned)m, 0));
                myidx[count + below] = (unsigned short)(c4 * 4 + c);
            }
            count += __popcll(m);                // wave-uniform running total
        }
    }

    __syncthreads();  // drain ds_writes before dynamic-indexed reads

    // ---- Phase 2: in-register h-sum, 64 indices per iteration ----
    float4 acc = make_float4(0.f, 0.f, 0.f, 0.f);
    const int nIter = (count + 63) >> 6;
    for (int t = 0; t < nIter; ++t) {
        int base = t * 64 + g * 4;               // group's 4 indices
        ushort4 idx4 = *(const ushort4*)&myidx[base];  // ds_read_b64, bcast in group
        const unsigned short* iq = (const unsigned short*)&idx4;
#pragma unroll
        for (int q = 0; q < 4; ++q) {
            float x    = (float)iq[q];
            float mval = (base + q < count) ? 1.0f : 0.0f;   // tail mask
#pragma unroll
            for (int c = 0; c < 4; ++c) {
                float h = fmaxf(fmaf(x, w1v[c], b1v[c]), 0.0f);
                (&acc.x)[c] = fmaf(h, mval, (&acc.x)[c]);
            }
        }
    }

    // Reduce across the 16 index-groups: butterfly over strides 4,8,16,32.
#pragma unroll
    for (int off = 4; off < 64; off <<= 1) {
        acc.x += __shfl_xor(acc.x, off);
        acc.y += __shfl_xor(acc.y, off);
        acc.z += __shfl_xor(acc.z, off);
        acc.w += __shfl_xor(acc.w, off);
    }
    // Lane l holds s[4*(l&3)+c]; broadcast all 16 to every lane.
    float s[HID];
#pragma unroll
    for (int a = 0; a < 4; ++a) {
        s[4 * a + 0] = __shfl(acc.x, a);
        s[4 * a + 1] = __shfl(acc.y, a);
        s[4 * a + 2] = __shfl(acc.z, a);
        s[4 * a + 3] = __shfl(acc.w, a);
    }

    // ---- Epilogue: emb[d] = (sum_k s[k]*W2[k][d] + count*b2[d]) / max(count,1)
    // Lane l owns dims 2l, 2l+1. W2 (8KB) / b2 (512B) are L1-hot.
    const float cnt = (float)count;
    const float inv = 1.0f / fmaxf(cnt, 1.0f);
    const float2* __restrict__ W2v = (const float2*)W2;    // [16][64] float2
    float2 bv = ((const float2*)b2)[lane];
    float e0 = cnt * bv.x;
    float e1 = cnt * bv.y;
#pragma unroll
    for (int k = 0; k < HID; ++k) {
        float2 w = W2v[k * 64 + lane];
        e0 = fmaf(s[k], w.x, e0);
        e1 = fmaf(s[k], w.y, e1);
    }
    ((float2*)out)[row * 64 + lane] = make_float2(e0 * inv, e1 * inv);
}

extern "C" void kernel_launch(void* const* d_in, const int* in_sizes, int n_in,
                              void* d_out, int out_size, void* d_ws, size_t ws_size,
                              hipStream_t stream) {
    const float* M  = (const float*)d_in[0];   // [50000, 2000]
    const float* W1 = (const float*)d_in[1];   // [1, 16]
    const float* b1 = (const float*)d_in[2];   // [16]
    const float* W2 = (const float*)d_in[3];   // [16, 128]
    const float* b2 = (const float*)d_in[4];   // [128]
    float* out = (float*)d_out;                // [50000, 128]

    fused_gather_mean_kernel<<<NUM_LEARNERS / 4, 256, 0, stream>>>(
        M, W1, b1, W2, b2, out);
}